// Round 1
// baseline (3121.770 us; speedup 1.0000x reference)
//
#include <hip/hip_runtime.h>
#include <math.h>

#define THREADS 256

// --- degree / dinv -----------------------------------------------------------

__global__ void k_init_cnt(int* cnt, int n) {
    int i = blockIdx.x * blockDim.x + threadIdx.x;
    if (i < n) cnt[i] = 1;  // self-loop
}

__global__ void k_count(const int* __restrict__ col, int e, int* __restrict__ cnt) {
    int i = blockIdx.x * blockDim.x + threadIdx.x;
    if (i < e) atomicAdd(&cnt[col[i]], 1);
}

__global__ void k_dinv(const int* __restrict__ cnt, float* __restrict__ dinv, int n) {
    int i = blockIdx.x * blockDim.x + threadIdx.x;
    if (i < n) dinv[i] = rsqrtf((float)cnt[i]);
}

// --- layer 1 transform: hs1[i] = dinv[i] * (x[i] @ W1); acc1 init = hs1 (self loop)

__global__ void k_xform1(const float* __restrict__ x, const float* __restrict__ W1,
                         const float* __restrict__ dinv,
                         float* __restrict__ hs1, float* __restrict__ acc1, int n) {
    __shared__ float sW[25 * 16];
    for (int t = threadIdx.x; t < 25 * 16; t += blockDim.x) sW[t] = W1[t];
    __syncthreads();
    int i = blockIdx.x * blockDim.x + threadIdx.x;
    if (i >= n) return;
    float xi[25];
#pragma unroll
    for (int k = 0; k < 25; k++) xi[k] = x[(size_t)i * 25 + k];
    float di = dinv[i];
#pragma unroll
    for (int c = 0; c < 16; c++) {
        float s = 0.f;
#pragma unroll
        for (int k = 0; k < 25; k++) s = fmaf(xi[k], sW[k * 16 + c], s);
        s *= di;
        hs1[(size_t)i * 16 + c] = s;
        acc1[(size_t)i * 16 + c] = s;
    }
}

// --- layer 1 edge scatter ----------------------------------------------------

__global__ void k_scatter1(const int* __restrict__ row, const int* __restrict__ col, int e,
                           const float* __restrict__ hs1, float* __restrict__ acc1) {
    int i = blockIdx.x * blockDim.x + threadIdx.x;
    if (i >= e) return;
    int j = row[i], t = col[i];
    const float4* src = (const float4*)(hs1 + (size_t)j * 16);
    float* dst = acc1 + (size_t)t * 16;
#pragma unroll
    for (int q = 0; q < 4; q++) {
        float4 v = src[q];
        atomicAdd(dst + q * 4 + 0, v.x);
        atomicAdd(dst + q * 4 + 1, v.y);
        atomicAdd(dst + q * 4 + 2, v.z);
        atomicAdd(dst + q * 4 + 3, v.w);
    }
}

// --- finish layer 1 (scale + bias + relu) and transform layer 2 --------------

__global__ void k_finish1_xform2(const float* __restrict__ acc1, const float* __restrict__ dinv,
                                 const float* __restrict__ b1, const float* __restrict__ W2,
                                 float* __restrict__ hs2, float* __restrict__ acc2, int n) {
    __shared__ float sW[16 * 2];
    __shared__ float sb[16];
    if (threadIdx.x < 32) sW[threadIdx.x] = W2[threadIdx.x];
    if (threadIdx.x < 16) sb[threadIdx.x] = b1[threadIdx.x];
    __syncthreads();
    int i = blockIdx.x * blockDim.x + threadIdx.x;
    if (i >= n) return;
    float di = dinv[i];
    float h[16];
#pragma unroll
    for (int k = 0; k < 16; k++)
        h[k] = fmaxf(fmaf(di, acc1[(size_t)i * 16 + k], sb[k]), 0.f);
    float s0 = 0.f, s1 = 0.f;
#pragma unroll
    for (int k = 0; k < 16; k++) {
        s0 = fmaf(h[k], sW[k * 2 + 0], s0);
        s1 = fmaf(h[k], sW[k * 2 + 1], s1);
    }
    s0 *= di; s1 *= di;
    hs2[(size_t)i * 2 + 0] = s0;
    hs2[(size_t)i * 2 + 1] = s1;
    acc2[(size_t)i * 2 + 0] = s0;  // self loop
    acc2[(size_t)i * 2 + 1] = s1;
}

// --- layer 2 edge scatter ----------------------------------------------------

__global__ void k_scatter2(const int* __restrict__ row, const int* __restrict__ col, int e,
                           const float* __restrict__ hs2, float* __restrict__ acc2) {
    int i = blockIdx.x * blockDim.x + threadIdx.x;
    if (i >= e) return;
    int j = row[i], t = col[i];
    float2 v = *(const float2*)(hs2 + (size_t)j * 2);
    atomicAdd(acc2 + (size_t)t * 2 + 0, v.x);
    atomicAdd(acc2 + (size_t)t * 2 + 1, v.y);
}

// --- finalize: scale + bias + log_softmax(2) ---------------------------------

__global__ void k_final(const float* __restrict__ acc2, const float* __restrict__ dinv,
                        const float* __restrict__ b2, float* __restrict__ out, int n) {
    int i = blockIdx.x * blockDim.x + threadIdx.x;
    if (i >= n) return;
    float di = dinv[i];
    float h0 = fmaf(di, acc2[(size_t)i * 2 + 0], b2[0]);
    float h1 = fmaf(di, acc2[(size_t)i * 2 + 1], b2[1]);
    float m = fmaxf(h0, h1);
    float lse = m + log1pf(expf(fminf(h0, h1) - m));
    out[(size_t)i * 2 + 0] = h0 - lse;
    out[(size_t)i * 2 + 1] = h1 - lse;
}

extern "C" void kernel_launch(void* const* d_in, const int* in_sizes, int n_in,
                              void* d_out, int out_size, void* d_ws, size_t ws_size,
                              hipStream_t stream) {
    const float* x  = (const float*)d_in[0];
    const int*   ei = (const int*)d_in[1];
    const float* W1 = (const float*)d_in[2];
    const float* b1 = (const float*)d_in[3];
    const float* W2 = (const float*)d_in[4];
    const float* b2 = (const float*)d_in[5];
    float* out = (float*)d_out;

    const int N = in_sizes[0] / 25;
    const int E = in_sizes[1] / 2;
    const int* row = ei;       // edge_index[0] = sources
    const int* col = ei + E;   // edge_index[1] = targets

    char* w = (char*)d_ws;
    int*   cnt  = (int*)w;    w += (size_t)N * sizeof(int);
    float* dinv = (float*)w;  w += (size_t)N * sizeof(float);
    float* hs1  = (float*)w;  w += (size_t)N * 16 * sizeof(float);
    float* acc1 = (float*)w;  w += (size_t)N * 16 * sizeof(float);
    float* hs2  = (float*)w;  w += (size_t)N * 2 * sizeof(float);
    float* acc2 = (float*)w;  w += (size_t)N * 2 * sizeof(float);

    const int gN = (N + THREADS - 1) / THREADS;
    const int gE = (E + THREADS - 1) / THREADS;

    k_init_cnt<<<gN, THREADS, 0, stream>>>(cnt, N);
    k_count<<<gE, THREADS, 0, stream>>>(col, E, cnt);
    k_dinv<<<gN, THREADS, 0, stream>>>(cnt, dinv, N);
    k_xform1<<<gN, THREADS, 0, stream>>>(x, W1, dinv, hs1, acc1, N);
    k_scatter1<<<gE, THREADS, 0, stream>>>(row, col, E, hs1, acc1);
    k_finish1_xform2<<<gN, THREADS, 0, stream>>>(acc1, dinv, b1, W2, hs2, acc2, N);
    k_scatter2<<<gE, THREADS, 0, stream>>>(row, col, E, hs2, acc2);
    k_final<<<gN, THREADS, 0, stream>>>(acc2, dinv, b2, out, N);
}

// Round 2
// 347.557 us; speedup vs baseline: 8.9821x; 8.9821x over previous
//
#include <hip/hip_runtime.h>
#include <math.h>

#define THREADS 256

// --- zero degree counters ----------------------------------------------------

__global__ void k_zero(int* cnt, int n) {
    int i = blockIdx.x * blockDim.x + threadIdx.x;
    if (i < n) cnt[i] = 0;
}

// --- count in-degree AND assign each edge its slot within its bucket ---------

__global__ void k_count_pos(const int* __restrict__ col, int e,
                            int* __restrict__ cnt, int* __restrict__ pos) {
    int i = blockIdx.x * blockDim.x + threadIdx.x;
    if (i < e) pos[i] = atomicAdd(&cnt[col[i]], 1);
}

// --- exclusive scan of cnt -> ptr (3 stages) ---------------------------------

__global__ void k_scan1(const int* __restrict__ cnt, int n,
                        int* __restrict__ excl, int* __restrict__ bsum) {
    __shared__ int s[256];
    int i = blockIdx.x * 256 + threadIdx.x;
    int v = (i < n) ? cnt[i] : 0;
    s[threadIdx.x] = v;
    __syncthreads();
    for (int off = 1; off < 256; off <<= 1) {
        int t = (threadIdx.x >= off) ? s[threadIdx.x - off] : 0;
        __syncthreads();
        s[threadIdx.x] += t;
        __syncthreads();
    }
    if (i < n) excl[i] = s[threadIdx.x] - v;  // exclusive within block
    if (threadIdx.x == 255) bsum[blockIdx.x] = s[255];
}

__global__ void k_scan2(int* __restrict__ bsum, int nb) {  // in-place exclusive, nb <= 1024
    __shared__ int s[1024];
    int v = (threadIdx.x < nb) ? bsum[threadIdx.x] : 0;
    s[threadIdx.x] = v;
    __syncthreads();
    for (int off = 1; off < 1024; off <<= 1) {
        int t = (threadIdx.x >= off) ? s[threadIdx.x - off] : 0;
        __syncthreads();
        s[threadIdx.x] += t;
        __syncthreads();
    }
    if (threadIdx.x < nb) bsum[threadIdx.x] = s[threadIdx.x] - v;
}

__global__ void k_scan3(int* __restrict__ excl, const int* __restrict__ boff, int n) {
    int i = blockIdx.x * 256 + threadIdx.x;
    if (i < n) excl[i] += boff[blockIdx.x];
}

// --- place edges into CSR (no atomics: pos assigned in k_count_pos) ----------

__global__ void k_place(const int* __restrict__ row, const int* __restrict__ col,
                        const int* __restrict__ pos, const int* __restrict__ ptr,
                        int e, int* __restrict__ csr) {
    int i = blockIdx.x * blockDim.x + threadIdx.x;
    if (i >= e) return;
    csr[ptr[col[i]] + pos[i]] = row[i];
}

// --- layer 1 transform: hs1[i] = dinv[i] * (x[i] @ W1) -----------------------

__global__ void k_xform1(const float* __restrict__ x, const float* __restrict__ W1,
                         const int* __restrict__ cnt,
                         float* __restrict__ hs1, int n) {
    __shared__ float sW[25 * 16];
    for (int t = threadIdx.x; t < 25 * 16; t += blockDim.x) sW[t] = W1[t];
    __syncthreads();
    int i = blockIdx.x * blockDim.x + threadIdx.x;
    if (i >= n) return;
    float xi[25];
#pragma unroll
    for (int k = 0; k < 25; k++) xi[k] = x[(size_t)i * 25 + k];
    float di = rsqrtf((float)(cnt[i] + 1));  // +1 self loop
#pragma unroll
    for (int c = 0; c < 16; c++) {
        float s = 0.f;
#pragma unroll
        for (int k = 0; k < 25; k++) s = fmaf(xi[k], sW[k * 16 + c], s);
        hs1[(size_t)i * 16 + c] = s * di;
    }
}

// --- gather layer 1 + bias/relu + @W2 (16 lanes per node) --------------------

__global__ void k_gather1(const int* __restrict__ ptr, const int* __restrict__ cnt,
                          const int* __restrict__ csr, const float* __restrict__ hs1,
                          const float* __restrict__ b1, const float* __restrict__ W2,
                          float* __restrict__ hs2, int n) {
    int g = threadIdx.x >> 4;   // 16 node-groups per block
    int c = threadIdx.x & 15;   // feature lane
    int node = blockIdx.x * 16 + g;
    if (node >= n) return;
    int beg = ptr[node], d = cnt[node];
    float acc = hs1[(size_t)node * 16 + c];  // self loop (hs1 already dinv-scaled)
    int e = 0;
    for (; e + 1 < d; e += 2) {
        int s0 = csr[beg + e], s1 = csr[beg + e + 1];
        acc += hs1[(size_t)s0 * 16 + c];
        acc += hs1[(size_t)s1 * 16 + c];
    }
    if (e < d) acc += hs1[(size_t)csr[beg + e] * 16 + c];
    float di = rsqrtf((float)(d + 1));
    float h = fmaxf(fmaf(di, acc, b1[c]), 0.f);  // layer-1 output feature c
    float p0 = h * W2[c * 2 + 0];
    float p1 = h * W2[c * 2 + 1];
#pragma unroll
    for (int m = 1; m < 16; m <<= 1) {
        p0 += __shfl_xor(p0, m, 16);
        p1 += __shfl_xor(p1, m, 16);
    }
    if (c == 0) {
        hs2[(size_t)node * 2 + 0] = di * p0;
        hs2[(size_t)node * 2 + 1] = di * p1;
    }
}

// --- gather layer 2 + bias + log_softmax(2) ----------------------------------

__global__ void k_gather2(const int* __restrict__ ptr, const int* __restrict__ cnt,
                          const int* __restrict__ csr, const float* __restrict__ hs2,
                          const float* __restrict__ b2, float* __restrict__ out, int n) {
    int node = blockIdx.x * blockDim.x + threadIdx.x;
    if (node >= n) return;
    int beg = ptr[node], d = cnt[node];
    float2 self = ((const float2*)hs2)[node];
    float a0 = self.x, a1 = self.y;
    int e = 0;
    for (; e + 1 < d; e += 2) {
        float2 v0 = ((const float2*)hs2)[csr[beg + e]];
        float2 v1 = ((const float2*)hs2)[csr[beg + e + 1]];
        a0 += v0.x + v1.x;
        a1 += v0.y + v1.y;
    }
    if (e < d) {
        float2 v = ((const float2*)hs2)[csr[beg + e]];
        a0 += v.x; a1 += v.y;
    }
    float di = rsqrtf((float)(d + 1));
    float h0 = fmaf(di, a0, b2[0]);
    float h1 = fmaf(di, a1, b2[1]);
    float m = fmaxf(h0, h1);
    float lse = m + log1pf(expf(fminf(h0, h1) - m));
    out[(size_t)node * 2 + 0] = h0 - lse;
    out[(size_t)node * 2 + 1] = h1 - lse;
}

extern "C" void kernel_launch(void* const* d_in, const int* in_sizes, int n_in,
                              void* d_out, int out_size, void* d_ws, size_t ws_size,
                              hipStream_t stream) {
    const float* x  = (const float*)d_in[0];
    const int*   ei = (const int*)d_in[1];
    const float* W1 = (const float*)d_in[2];
    const float* b1 = (const float*)d_in[3];
    const float* W2 = (const float*)d_in[4];
    const float* b2 = (const float*)d_in[5];
    float* out = (float*)d_out;

    const int N = in_sizes[0] / 25;
    const int E = in_sizes[1] / 2;
    const int* row = ei;       // sources
    const int* col = ei + E;   // targets

    char* w = (char*)d_ws;
    int*   cnt  = (int*)w;    w += (size_t)N * sizeof(int);
    int*   ptr  = (int*)w;    w += (size_t)N * sizeof(int);
    int*   pos  = (int*)w;    w += (size_t)E * sizeof(int);
    int*   csr  = (int*)w;    w += (size_t)E * sizeof(int);
    int*   bsum = (int*)w;    w += (size_t)1024 * sizeof(int);
    float* hs1  = (float*)w;  w += (size_t)N * 16 * sizeof(float);
    float* hs2  = (float*)w;  w += (size_t)N * 2 * sizeof(float);

    const int gN = (N + THREADS - 1) / THREADS;
    const int gE = (E + THREADS - 1) / THREADS;
    const int NB = (N + 255) / 256;  // blocks in scan1 (must be <= 1024)

    k_zero<<<gN, THREADS, 0, stream>>>(cnt, N);
    k_count_pos<<<gE, THREADS, 0, stream>>>(col, E, cnt, pos);
    k_scan1<<<NB, 256, 0, stream>>>(cnt, N, ptr, bsum);
    k_scan2<<<1, 1024, 0, stream>>>(bsum, NB);
    k_scan3<<<NB, 256, 0, stream>>>(ptr, bsum, N);
    k_place<<<gE, THREADS, 0, stream>>>(row, col, pos, ptr, E, csr);
    k_xform1<<<gN, THREADS, 0, stream>>>(x, W1, cnt, hs1, N);
    k_gather1<<<(N + 15) / 16, 256, 0, stream>>>(ptr, cnt, csr, hs1, b1, W2, hs2, N);
    k_gather2<<<gN, THREADS, 0, stream>>>(ptr, cnt, csr, hs2, b2, out, N);
}